// Round 11
// baseline (423.026 us; speedup 1.0000x reference)
//
#include <hip/hip_runtime.h>
#include <hip/hip_fp16.h>

// ---------------------------------------------------------------------------
// FormulaNet GCN forward: 3x GCNConv(128) + mean-pool(512 graphs) + dense.
// R18 layer-1 linearity swap | R21 int8 | R22 fp8 e4m3 rows | R23 prefetch
// R24 aggL1 fusion [BEST 262.4]
// AGG FLOOR (R17-R24): 83MB FETCH / 66us = 1.5 TB/s of 128B-random HBM =
//      DRAM random-access ceiling (~20% of peak). Bytes/segments/dep-chain/
//      MLP-depth levers all nulled. aggmm+aggsum are done.
// R25 LESSON: fineB rebalance null -> the tail cost is the bucket-sort
//      machinery itself, not its balance.
// R26: delete the CSR bucket sort. Counting-sort at node granularity with
//      fixed 64-slot col windows (Poisson(16) max deg ~45 << 64):
//      prep: atomicAdd(degCnt[dst]) (L2-resident, no LDS/staged);
//      k_mid: dis/h0s from degCnt + scatter col[(dst<<6)+cur++]=src
//      (random 4B writes = L2-absorbed, R20 lesson). rpe/staged/fineB
//      deleted; agg kernels use r0=node<<6, r1=r0+min(deg,64).
// ---------------------------------------------------------------------------

typedef _Float16 half8 __attribute__((ext_vector_type(8)));
typedef float f32x4 __attribute__((ext_vector_type(4)));
typedef float f32x2 __attribute__((ext_vector_type(2)));

#define RFL __builtin_amdgcn_readfirstlane

// ---- prep: deg-hist | layer1(4-dim h0) | cvtW | bounds | zero(sums) ----
__global__ __launch_bounds__(512) void k_prep(
        const float* __restrict__ x, const float* __restrict__ Wd1,
        const float* __restrict__ bd1, __half* __restrict__ h0,
        const float* __restrict__ W2, const float* __restrict__ W3,
        __half* __restrict__ WT2, __half* __restrict__ WT3,
        const int* __restrict__ batch, int* __restrict__ gs,
        const int* __restrict__ dst, int* __restrict__ degCnt,
        float* __restrict__ sums,
        int N, int NG, int E, int BINB, int L1B, int NB1) {
    int bid = blockIdx.x;
    int t = threadIdx.x;
    if (bid < BINB) {
        // ---- degree histogram: 4096 edges/block, L2-resident atomics
        int e0 = bid * 4096 + t;
#pragma unroll
        for (int k = 0; k < 8; k++) {
            int e = e0 + k * 512;
            if (e < E) atomicAdd(&degCnt[dst[e]], 1);
        }
    } else if (bid < BINB + L1B) {
        // ---- layer1 front: h0 = relu(x@Wd1+bd1), 4-dim fp16 (8 B/node)
        int node = (bid - BINB) * 512 + t;
        if (node < N) {
            float4 xv = ((const float4*)x)[node];
            float h[4];
#pragma unroll
            for (int k = 0; k < 4; k++) {
                float v = xv.x * Wd1[k] + xv.y * Wd1[4 + k]
                        + xv.z * Wd1[8 + k] + xv.w * Wd1[12 + k] + bd1[k];
                h[k] = fmaxf(v, 0.f);
            }
            __half2 o01 = __floats2half2_rn(h[0], h[1]);
            __half2 o23 = __floats2half2_rn(h[2], h[3]);
            uint2 pk;
            pk.x = *(unsigned*)&o01; pk.y = *(unsigned*)&o23;
            *(uint2*)(h0 + (size_t)node * 4) = pk;
        }
    } else if (bid < BINB + L1B + 32) {
        // ---- cvtW: W fp32 [k][n] -> WT fp16 [n][k], both layers
        int t2 = (bid - BINB - L1B) * 512 + t;      // 0..16383
        int k = t2 >> 7, nn = t2 & 127;
        WT2[nn * 128 + k] = __float2half_rn(W2[t2]);
        WT3[nn * 128 + k] = __float2half_rn(W3[t2]);
    } else if (bid < BINB + L1B + 32 + NB1) {
        // ---- bounds: batch sorted -> per-graph node ranges
        int i = (bid - BINB - L1B - 32) * 512 + t;
        if (i >= N) return;
        int b = batch[i];
        int prev = (i == 0) ? -1 : batch[i - 1];
        for (int g2 = prev + 1; g2 <= b; ++g2) gs[g2] = i;
        if (i == N - 1)
            for (int g2 = b + 1; g2 <= NG; ++g2) gs[g2] = N;
    } else {
        // ---- zero sums
        int idx = (bid - BINB - L1B - 32 - NB1) * 512 + t;
        if (idx < NG * 128) sums[idx] = 0.f;
    }
}

// ---- mid: [nodes] dis = rsqrt(deg+1), h0s = dis*h0 | [edges] scatter
// col[(dst<<6) + cur[dst]++] = src (random 4B writes, L2-absorbed).
__global__ __launch_bounds__(512) void k_mid(
        const int* __restrict__ dst, const int* __restrict__ src,
        const int* __restrict__ degCnt, int* __restrict__ cur,
        int* __restrict__ col, const __half* __restrict__ h0,
        __half* __restrict__ h0s, float* __restrict__ dis,
        int N, int E, int NODB) {
    int bid = blockIdx.x;
    int t = threadIdx.x;
    if (bid < NODB) {
        int node = bid * 512 + t;
        if (node < N) {
            float dloc = rsqrtf((float)(degCnt[node] + 1));  // +1 self-loop
            dis[node] = dloc;
            uint2 hv = *(const uint2*)(h0 + (size_t)node * 4);
            float2 a01 = __half22float2(*(__half2*)&hv.x);
            float2 a23 = __half22float2(*(__half2*)&hv.y);
            __half2 o01 = __floats2half2_rn(a01.x * dloc, a01.y * dloc);
            __half2 o23 = __floats2half2_rn(a23.x * dloc, a23.y * dloc);
            uint2 pk;
            pk.x = *(unsigned*)&o01; pk.y = *(unsigned*)&o23;
            *(uint2*)(h0s + (size_t)node * 4) = pk;
        }
    } else {
        int e0 = (bid - NODB) * 4096 + t;
#pragma unroll
        for (int k = 0; k < 8; k++) {
            int e = e0 + k * 512;
            if (e < E) {
                int d = dst[e];
                int pos = atomicAdd(&cur[d], 1);
                if (pos < 64)                       // slot cap (P(deg>64)~0)
                    col[((size_t)d << 6) + pos] = src[e];
            }
        }
    }
}

// ---- helpers ----
__device__ __forceinline__ void addv4(float a[4], uint2 v) {
    float2 x01 = __half22float2(*(__half2*)&v.x);
    float2 x23 = __half22float2(*(__half2*)&v.y);
    a[0] += x01.x; a[1] += x01.y; a[2] += x23.x; a[3] += x23.y;
}

// ---- fp8 helpers: pack 8 fp32 (one seg of a row) -> uint2 of e4m3 ----
__device__ __forceinline__ uint2 pack_fp8x8(const float v[8]) {
    int a = 0, b = 0;
    a = __builtin_amdgcn_cvt_pk_fp8_f32(v[0], v[1], a, false);
    a = __builtin_amdgcn_cvt_pk_fp8_f32(v[2], v[3], a, true);
    b = __builtin_amdgcn_cvt_pk_fp8_f32(v[4], v[5], b, false);
    b = __builtin_amdgcn_cvt_pk_fp8_f32(v[6], v[7], b, true);
    return make_uint2((unsigned)a, (unsigned)b);
}

__device__ __forceinline__ void accf8(float acc[4], unsigned u) {
    f32x2 lo = __builtin_amdgcn_cvt_pk_f32_fp8(u, false);
    f32x2 hi = __builtin_amdgcn_cvt_pk_f32_fp8(u, true);
    acc[0] += lo[0]; acc[1] += lo[1]; acc[2] += hi[0]; acc[3] += hi[1];
}

// ---- fused layer1: 4-dim agg (16 threads/node, 1 thread/edge at deg~16,
// h0s L2-resident) + 16-lane shfl reduce + MFMA back-end.
__global__ __launch_bounds__(256) void k_aggL1(
        const __half* __restrict__ h0s, const int* __restrict__ deg,
        const float* __restrict__ dis, const int* __restrict__ col,
        const float* __restrict__ Wg1, const float* __restrict__ b1,
        const __half* __restrict__ WT2, unsigned char* __restrict__ qout,
        int n) {
    __shared__ float sW[512];
    __shared__ float sB[128];
    __shared__ float sAgg[16][4];
    __shared__ float sDis[16];
    __shared__ _Float16 sH[16 * 136];
    __shared__ _Float16 sO[16 * 136];
    int t = threadIdx.x;
    sW[t] = Wg1[t];
    sW[t + 256] = Wg1[t + 256];
    if (t < 128) sB[t] = b1[t];
    int node0 = blockIdx.x * 16;
    if (t < 16) sDis[t] = (node0 + t < n) ? dis[node0 + t] : 0.f;
    int g = t >> 4, sub = t & 15;
    int ng = node0 + g;
    float a[4] = {0.f, 0.f, 0.f, 0.f};
    if (ng < n) {
        int dv = deg[ng]; if (dv > 64) dv = 64;
        int r0 = ng << 6;
        for (int e = sub; e < dv; e += 16) {
            uint2 vv = *(const uint2*)(h0s + (size_t)col[r0 + e] * 4);
            addv4(a, vv);
        }
    }
    // reduce across the node's 16 lanes (same wave: groups are 16-aligned)
#pragma unroll
    for (int k = 0; k < 4; k++) {
        a[k] += __shfl_xor(a[k], 1);
        a[k] += __shfl_xor(a[k], 2);
        a[k] += __shfl_xor(a[k], 4);
        a[k] += __shfl_xor(a[k], 8);
    }
    if (ng < n) {
        // self-loop (h0s pre-scaled by dis): add once, post-reduce
        uint2 sv = *(const uint2*)(h0s + (size_t)ng * 4);
        float2 s01 = __half22float2(*(__half2*)&sv.x);
        float2 s23 = __half22float2(*(__half2*)&sv.y);
        a[0] += s01.x; a[1] += s01.y; a[2] += s23.x; a[3] += s23.y;
        float di = dis[ng];
        // static-index select (no runtime index into reg array)
        float av = (sub == 0) ? a[0] : (sub == 1) ? a[1]
                 : (sub == 2) ? a[2] : a[3];
        if (sub < 4) sAgg[g][sub] = av * di;    // same-wave write/read ok
    }
    __syncthreads();    // sW/sB/sDis/sAgg ready for all waves
    int row = t >> 4, seg = t & 15;
    int nodeR = node0 + row;
    float4 av4 = make_float4(sAgg[row][0], sAgg[row][1],
                             sAgg[row][2], sAgg[row][3]);
    half8 hv;
#pragma unroll
    for (int u = 0; u < 8; u++) {
        int j = seg * 8 + u;
        float vv = sB[j] + av4.x * sW[j] + av4.y * sW[128 + j]
                 + av4.z * sW[256 + j] + av4.w * sW[384 + j];
        hv[u] = (_Float16)fmaxf(vv, 0.f);
    }
    *(half8*)&sH[row * 136 + seg * 8] = hv;
    __syncthreads();
    // mm: wave covers cols [wave*32, wave*32+32) for all 16 rows
    int wave = t >> 6, lane = t & 63;
    int q = lane >> 4, c = lane & 15;
    int n0c = wave * 32;
    f32x4 acc0 = {0.f, 0.f, 0.f, 0.f}, acc1 = {0.f, 0.f, 0.f, 0.f};
#pragma unroll
    for (int ks = 0; ks < 4; ks++) {
        int k0 = ks * 32;
        half8 av  = *(half8*)&sH[c * 136 + k0 + q * 8];
        half8 b0 = *(const half8*)(WT2 + (size_t)(n0c + c) * 128 + k0 + q * 8);
        half8 b1v = *(const half8*)(WT2 + (size_t)(n0c + 16 + c) * 128 + k0 + q * 8);
        acc0 = __builtin_amdgcn_mfma_f32_16x16x32_f16(av, b0, acc0, 0, 0, 0);
        acc1 = __builtin_amdgcn_mfma_f32_16x16x32_f16(av, b1v, acc1, 0, 0, 0);
    }
#pragma unroll
    for (int r = 0; r < 4; r++) {
        int rr = q * 4 + r;
        sO[rr * 136 + n0c + c]      = (_Float16)(acc0[r] * sDis[rr]);
        sO[rr * 136 + n0c + 16 + c] = (_Float16)(acc1[r] * sDis[rr]);
    }
    __syncthreads();
    // fp8 pack epilogue
    half8 ov = *(half8*)&sO[row * 136 + seg * 8];
    float vv[8];
#pragma unroll
    for (int u = 0; u < 8; u++) vv[u] = (float)ov[u];
    if (nodeR < n)
        *(uint2*)(qout + (size_t)nodeR * 128 + seg * 8) = pack_fp8x8(vv);
}

// ---- fp8 gather core (R23 prefetch, R24 8-deep): half-wave hf covers
// edge 2p+hf's FULL row (4 B/lane = 4 e4m3, lanes sl=0..31 -> feats
// 4sl..4sl+3 = 128 B row). nloc <= 64 (slot cap).
__device__ __forceinline__ void agg_chunk_f8(
        const unsigned char* __restrict__ g, int colv, int nloc,
        int hf, int sl, float acc[4]) {
    int npair = nloc >> 1;
    int p = 0;
    for (; p + 7 < npair; p += 8) {
        int i2 = p * 2 + hf;
        int s0 = __shfl(colv, i2);
        int s1 = __shfl(colv, i2 + 2);
        int s2 = __shfl(colv, i2 + 4);
        int s3 = __shfl(colv, i2 + 6);
        int s4 = __shfl(colv, i2 + 8);
        int s5 = __shfl(colv, i2 + 10);
        int s6 = __shfl(colv, i2 + 12);
        int s7 = __shfl(colv, i2 + 14);
        unsigned u0 = *(const unsigned*)(g + (size_t)s0 * 128 + sl * 4);
        unsigned u1 = *(const unsigned*)(g + (size_t)s1 * 128 + sl * 4);
        unsigned u2 = *(const unsigned*)(g + (size_t)s2 * 128 + sl * 4);
        unsigned u3 = *(const unsigned*)(g + (size_t)s3 * 128 + sl * 4);
        unsigned u4 = *(const unsigned*)(g + (size_t)s4 * 128 + sl * 4);
        unsigned u5 = *(const unsigned*)(g + (size_t)s5 * 128 + sl * 4);
        unsigned u6 = *(const unsigned*)(g + (size_t)s6 * 128 + sl * 4);
        unsigned u7 = *(const unsigned*)(g + (size_t)s7 * 128 + sl * 4);
        accf8(acc, u0); accf8(acc, u1); accf8(acc, u2); accf8(acc, u3);
        accf8(acc, u4); accf8(acc, u5); accf8(acc, u6); accf8(acc, u7);
    }
    for (; p + 3 < npair; p += 4) {
        int i2 = p * 2 + hf;
        int s0 = __shfl(colv, i2);
        int s1 = __shfl(colv, i2 + 2);
        int s2 = __shfl(colv, i2 + 4);
        int s3 = __shfl(colv, i2 + 6);
        unsigned u0 = *(const unsigned*)(g + (size_t)s0 * 128 + sl * 4);
        unsigned u1 = *(const unsigned*)(g + (size_t)s1 * 128 + sl * 4);
        unsigned u2 = *(const unsigned*)(g + (size_t)s2 * 128 + sl * 4);
        unsigned u3 = *(const unsigned*)(g + (size_t)s3 * 128 + sl * 4);
        accf8(acc, u0); accf8(acc, u1); accf8(acc, u2); accf8(acc, u3);
    }
    for (; p < npair; ++p) {
        int s0 = __shfl(colv, p * 2 + hf);
        unsigned u0 = *(const unsigned*)(g + (size_t)s0 * 128 + sl * 4);
        accf8(acc, u0);
    }
    if (nloc & 1) {                         // odd tail: half 1 contributes 0
        int s0 = __shfl(colv, nloc - 1);
        unsigned u0 = *(const unsigned*)(g + (size_t)s0 * 128 + sl * 4);
        if (!hf) accf8(acc, u0);
    }
}

// per-node agg: colv = col[(node<<6)+lane] prefetched by caller before any
// gathers; nloc = min(deg,64).
__device__ __forceinline__ void agg_node_f8v(
        const unsigned char* __restrict__ g, int node, int colv, int nloc,
        int hf, int sl, float acc[4]) {
    acc[0] = acc[1] = acc[2] = acc[3] = 0.f;
    if (!hf) {   // self-loop on half 0 only (rows pre-scaled by dis)
        unsigned su = *(const unsigned*)(g + (size_t)node * 128 + sl * 4);
        accf8(acc, su);
    }
    agg_chunk_f8(g, colv, nloc, hf, sl, acc);
#pragma unroll
    for (int k = 0; k < 4; k++) acc[k] += __shfl_xor(acc[k], 32);
}

// fused GCN layer (fp8 in / fp8 out): block = 16 nodes (4 waves x 4
// serial). Prefetch-then-burst agg -> LDS rows -> mfma -> fp8 rows.
__global__ __launch_bounds__(256) void k_aggmm(
        const unsigned char* __restrict__ qin, const int* __restrict__ deg,
        const int* __restrict__ col, const float* __restrict__ dis,
        const float* __restrict__ bias, const __half* __restrict__ WT,
        unsigned char* __restrict__ qout, int n) {
    __shared__ _Float16 sH[16 * 136];
    __shared__ _Float16 sO[16 * 136];
    __shared__ float sDis[16];
    int t = threadIdx.x;
    int wave = t >> 6, lane = t & 63;
    int hf = lane >> 5, sl = lane & 31;
    int node0 = blockIdx.x * 16;
    if (t < 16) sDis[t] = (node0 + t < n) ? dis[node0 + t] : 0.f;
    float4 bb = ((const float4*)bias)[sl];
    int nodeA = node0 + wave * 4;
    // --- prefetch: 4x deg then 4x col vectors, BEFORE any gather ---
    int nd0 = RFL(nodeA), nd1 = RFL(nodeA + 1);
    int nd2 = RFL(nodeA + 2), nd3 = RFL(nodeA + 3);
    int dg0 = (nd0 < n) ? RFL(deg[nd0]) : 0;
    int dg1 = (nd1 < n) ? RFL(deg[nd1]) : 0;
    int dg2 = (nd2 < n) ? RFL(deg[nd2]) : 0;
    int dg3 = (nd3 < n) ? RFL(deg[nd3]) : 0;
    if (dg0 > 64) dg0 = 64;
    if (dg1 > 64) dg1 = 64;
    if (dg2 > 64) dg2 = 64;
    if (dg3 > 64) dg3 = 64;
    int cv0 = (nd0 < n) ? col[((size_t)nd0 << 6) + lane] : 0;
    int cv1 = (nd1 < n) ? col[((size_t)nd1 << 6) + lane] : 0;
    int cv2 = (nd2 < n) ? col[((size_t)nd2 << 6) + lane] : 0;
    int cv3 = (nd3 < n) ? col[((size_t)nd3 << 6) + lane] : 0;
    float acc[4];
#define AGGMM_NODE(I, ND, DG, CV)                                            \
    if (ND < n) {                                                            \
        agg_node_f8v(qin, ND, CV, DG, hf, sl, acc);                          \
        if (hf == 0) {                                                       \
            float di = sDis[wave * 4 + I];                                   \
            __half2 o01 = __floats2half2_rn(                                 \
                fmaxf(fmaf(di, acc[0], bb.x), 0.f),                          \
                fmaxf(fmaf(di, acc[1], bb.y), 0.f));                         \
            __half2 o23 = __floats2half2_rn(                                 \
                fmaxf(fmaf(di, acc[2], bb.z), 0.f),                          \
                fmaxf(fmaf(di, acc[3], bb.w), 0.f));                         \
            uint2 pk;                                                        \
            pk.x = *(unsigned*)&o01; pk.y = *(unsigned*)&o23;                \
            *(uint2*)&sH[(wave * 4 + I) * 136 + sl * 4] = pk;                \
        }                                                                    \
    }
    __syncthreads();   // sDis ready (also orders sH writes vs later reads)
    AGGMM_NODE(0, nd0, dg0, cv0)
    AGGMM_NODE(1, nd1, dg1, cv1)
    AGGMM_NODE(2, nd2, dg2, cv2)
    AGGMM_NODE(3, nd3, dg3, cv3)
#undef AGGMM_NODE
    __syncthreads();
    // mm: wave covers cols [wave*32, wave*32+32) for all 16 rows
    int q = lane >> 4, c = lane & 15;
    int n0 = wave * 32;
    f32x4 acc0 = {0.f, 0.f, 0.f, 0.f}, acc1 = {0.f, 0.f, 0.f, 0.f};
#pragma unroll
    for (int ks = 0; ks < 4; ks++) {
        int k0 = ks * 32;
        half8 a  = *(half8*)&sH[c * 136 + k0 + q * 8];
        half8 b0 = *(const half8*)(WT + (size_t)(n0 + c) * 128 + k0 + q * 8);
        half8 b1 = *(const half8*)(WT + (size_t)(n0 + 16 + c) * 128 + k0 + q * 8);
        acc0 = __builtin_amdgcn_mfma_f32_16x16x32_f16(a, b0, acc0, 0, 0, 0);
        acc1 = __builtin_amdgcn_mfma_f32_16x16x32_f16(a, b1, acc1, 0, 0, 0);
    }
#pragma unroll
    for (int r = 0; r < 4; r++) {
        int rr = q * 4 + r;
        sO[rr * 136 + n0 + c]      = (_Float16)(acc0[r] * sDis[rr]);
        sO[rr * 136 + n0 + 16 + c] = (_Float16)(acc1[r] * sDis[rr]);
    }
    __syncthreads();
    // fp8 pack epilogue
    int lr2 = t >> 4, seg = t & 15;
    int rowN = node0 + lr2;
    half8 ov = *(half8*)&sO[lr2 * 136 + seg * 8];
    float vv[8];
#pragma unroll
    for (int u = 0; u < 8; u++) vv[u] = (float)ov[u];
    if (rowN < n)
        *(uint2*)(qout + (size_t)rowN * 128 + seg * 8) = pack_fp8x8(vv);
}

// fused layer-3 agg + mean-pool (fp8 input). Single-graph blocks (~92%):
// per-wave register partials -> private LDS slots -> one barrier ->
// 128 global atomics. Boundary: per-wave flush.
__global__ __launch_bounds__(256) void k_aggsum(
        const unsigned char* __restrict__ qin, const int* __restrict__ deg,
        const int* __restrict__ col, const float* __restrict__ dis,
        const float* __restrict__ bias, const int* __restrict__ batch,
        float* __restrict__ sums, int n) {
    __shared__ float ls[4][128];
    int t = threadIdx.x;
    int wave = t >> 6, lane = t & 63;
    int hf = lane >> 5, sl = lane & 31;
    int nodeBase = blockIdx.x * 16;
    if (nodeBase >= n) return;
    int lastNode = min(nodeBase + 15, n - 1);
    int b0 = RFL(batch[nodeBase]);
    bool uni = (RFL(batch[lastNode]) == b0);
    float4 bb = ((const float4*)bias)[sl];
    float sx[4] = {0.f, 0.f, 0.f, 0.f};
    int curb = b0;
    int nodeA = nodeBase + wave * 4;
    // --- prefetch: 4x deg then 4x col vectors ---
    int nd0 = RFL(nodeA), nd1 = RFL(nodeA + 1);
    int nd2 = RFL(nodeA + 2), nd3 = RFL(nodeA + 3);
    int dg0 = (nd0 < n) ? RFL(deg[nd0]) : 0;
    int dg1 = (nd1 < n) ? RFL(deg[nd1]) : 0;
    int dg2 = (nd2 < n) ? RFL(deg[nd2]) : 0;
    int dg3 = (nd3 < n) ? RFL(deg[nd3]) : 0;
    if (dg0 > 64) dg0 = 64;
    if (dg1 > 64) dg1 = 64;
    if (dg2 > 64) dg2 = 64;
    if (dg3 > 64) dg3 = 64;
    int cv0 = (nd0 < n) ? col[((size_t)nd0 << 6) + lane] : 0;
    int cv1 = (nd1 < n) ? col[((size_t)nd1 << 6) + lane] : 0;
    int cv2 = (nd2 < n) ? col[((size_t)nd2 << 6) + lane] : 0;
    int cv3 = (nd3 < n) ? col[((size_t)nd3 << 6) + lane] : 0;
    float acc[4];
#define AGGSUM_NODE(ND, DG, CV)                                              \
    if (ND < n) {                                                            \
        agg_node_f8v(qin, ND, CV, DG, hf, sl, acc);                          \
        float di = dis[ND];                                                  \
        float o0 = fmaxf(fmaf(di, acc[0], bb.x), 0.f);                       \
        float o1 = fmaxf(fmaf(di, acc[1], bb.y), 0.f);                       \
        float o2 = fmaxf(fmaf(di, acc[2], bb.z), 0.f);                       \
        float o3 = fmaxf(fmaf(di, acc[3], bb.w), 0.f);                       \
        if (!uni) {                                                          \
            int b = RFL(batch[ND]);                                          \
            if (b != curb) {                                                 \
                if (hf == 0) {                                               \
                    atomicAdd(&sums[(size_t)curb * 128 + sl * 4 + 0], sx[0]);\
                    atomicAdd(&sums[(size_t)curb * 128 + sl * 4 + 1], sx[1]);\
                    atomicAdd(&sums[(size_t)curb * 128 + sl * 4 + 2], sx[2]);\
                    atomicAdd(&sums[(size_t)curb * 128 + sl * 4 + 3], sx[3]);\
                }                                                            \
                sx[0] = sx[1] = sx[2] = sx[3] = 0.f;                         \
                curb = b;                                                    \
            }                                                                \
        }                                                                    \
        sx[0] += o0; sx[1] += o1; sx[2] += o2; sx[3] += o3;                  \
    }
    AGGSUM_NODE(nd0, dg0, cv0)
    AGGSUM_NODE(nd1, dg1, cv1)
    AGGSUM_NODE(nd2, dg2, cv2)
    AGGSUM_NODE(nd3, dg3, cv3)
#undef AGGSUM_NODE
    if (uni) {
        // slot-exclusive LDS write (hf==0 lanes cover all 128 feats)
        if (hf == 0) {
            ls[wave][sl * 4 + 0] = sx[0];
            ls[wave][sl * 4 + 1] = sx[1];
            ls[wave][sl * 4 + 2] = sx[2];
            ls[wave][sl * 4 + 3] = sx[3];
        }
        __syncthreads();
        if (t < 128) {
            float v = ls[0][t] + ls[1][t] + ls[2][t] + ls[3][t];
            atomicAdd(&sums[(size_t)b0 * 128 + t], v);
        }
    } else {
        if (hf == 0) {
            atomicAdd(&sums[(size_t)curb * 128 + sl * 4 + 0], sx[0]);
            atomicAdd(&sums[(size_t)curb * 128 + sl * 4 + 1], sx[1]);
            atomicAdd(&sums[(size_t)curb * 128 + sl * 4 + 2], sx[2]);
            atomicAdd(&sums[(size_t)curb * 128 + sl * 4 + 3], sx[3]);
        }
    }
}

// head: pooled = sums/cnt; out = pooled @ Wd2 + bd2. One block per graph.
__global__ __launch_bounds__(128) void k_head(
        const float* __restrict__ sums, const int* __restrict__ gs,
        const float* __restrict__ Wd2, const float* __restrict__ bd2,
        float* __restrict__ out) {
    int gidx = blockIdx.x;
    int j = threadIdx.x;
    int c = gs[gidx + 1] - gs[gidx];
    float inv = 1.0f / (float)(c > 1 ? c : 1);
    __shared__ float sp[128];
    sp[j] = sums[(size_t)gidx * 128 + j] * inv;
    __syncthreads();
    float o = bd2[j];
#pragma unroll 8
    for (int k = 0; k < 128; k++) o = fmaf(sp[k], Wd2[k * 128 + j], o);
    out[gidx * 128 + j] = o;
}

extern "C" void kernel_launch(void* const* d_in, const int* in_sizes, int n_in,
                              void* d_out, int out_size, void* d_ws, size_t ws_size,
                              hipStream_t stream) {
    const float* x   = (const float*)d_in[0];
    const int*  ei   = (const int*)d_in[1];
    const int* batch = (const int*)d_in[2];
    const float* Wd1 = (const float*)d_in[3];
    const float* bd1 = (const float*)d_in[4];
    const float* Wg1 = (const float*)d_in[5];
    const float* bg1 = (const float*)d_in[6];
    const float* Wg2 = (const float*)d_in[7];
    const float* bg2 = (const float*)d_in[8];
    const float* Wg3 = (const float*)d_in[9];
    const float* bg3 = (const float*)d_in[10];
    const float* Wd2 = (const float*)d_in[11];
    const float* bd2 = (const float*)d_in[12];
    float* out = (float*)d_out;

    int N  = in_sizes[0] / 4;       // N_FEAT = 4
    int E  = in_sizes[1] / 2;       // edge_index is [2, E]
    int NG = out_size / 128;        // 512 graphs
    const int* srcIdx = ei;
    const int* dstIdx = ei + E;

    char* p = (char*)d_ws;
    auto alloc = [&](size_t bytes) -> char* {
        char* r = p;
        p += (bytes + 255) & ~(size_t)255;
        return r;
    };
    int*    degCnt  = (int*)alloc((size_t)N * 8);     // deg | cur (contig)
    int*    cur     = degCnt + N;
    int*    col     = (int*)alloc((size_t)N * 64 * 4);   // 25.6 MB slots
    float*  dis     = (float*)alloc((size_t)N * 4);
    int*    gs      = (int*)alloc(((size_t)NG + 1) * 4);
    float*  sums    = (float*)alloc((size_t)NG * 128 * 4);
    __half* WT2     = (__half*)alloc(16384 * 2);
    __half* WT3     = (__half*)alloc(16384 * 2);
    unsigned char* qB = (unsigned char*)alloc((size_t)N * 128);   // 12.8 MB
    unsigned char* qA = (unsigned char*)alloc((size_t)N * 128);   // 12.8 MB
    __half* h0      = (__half*)alloc((size_t)N * 4 * 2);          // 0.8 MB
    __half* h0s     = (__half*)alloc((size_t)N * 4 * 2);          // 0.8 MB
    (void)ws_size; (void)n_in;

    int BINB = (E + 4095) / 4096;               // 391
    int L1B  = (N + 511) / 512;                 // 196
    int NB1  = (N + 511) / 512;                 // 196
    int ZB   = (NG * 128 + 511) / 512;          // 128
    int prepB = BINB + L1B + 32 + NB1 + ZB;
    int NODB  = (N + 511) / 512;                // 196
    int midB  = NODB + BINB;                    // 587
    int nb16  = (N + 15) / 16;                  // 6250

    hipMemsetAsync(degCnt, 0, (size_t)N * 8, stream);   // deg + cur

    k_prep<<<prepB, 512, 0, stream>>>(x, Wd1, bd1, h0, Wg2, Wg3, WT2, WT3,
                                      batch, gs, dstIdx, degCnt, sums,
                                      N, NG, E, BINB, L1B, NB1);
    k_mid<<<midB, 512, 0, stream>>>(dstIdx, srcIdx, degCnt, cur, col,
                                    h0, h0s, dis, N, E, NODB);

    // layer1: fused 4-dim agg (16 thr/node, L2-resident) + MFMA back-end:
    // qB = fp8(dis * (relu(agg@Wg1+b1) @ W2))
    k_aggL1<<<nb16, 256, 0, stream>>>(h0s, degCnt, dis, col, Wg1, bg1, WT2,
                                      qB, N);
    // layer2: fp8-row fused agg+mm -> qA
    k_aggmm<<<nb16, 256, 0, stream>>>(qB, degCnt, col, dis, bg2, WT3, qA, N);
    // layer3 + pool (fp8 input)
    k_aggsum<<<nb16, 256, 0, stream>>>(qA, degCnt, col, dis, bg3, batch,
                                       sums, N);

    k_head<<<NG, 128, 0, stream>>>(sums, gs, Wd2, bd2, out);
}

// Round 12
// 261.928 us; speedup vs baseline: 1.6150x; 1.6150x over previous
//
#include <hip/hip_runtime.h>
#include <hip/hip_fp16.h>

// ---------------------------------------------------------------------------
// FormulaNet GCN forward: 3x GCNConv(128) + mean-pool(512 graphs) + dense.
// R2 fp16 | R4 bucket CSR | R7 prep mega-kernel | R12 aggsum LDS slots
// R18 layer-1 linearity swap | R21 int8 | R22 fp8 e4m3 | R23 prefetch
// R24 aggL1 fusion [BEST 262.4] | R27 = R24 reverted verbatim.
// AGG FLOOR (R17-R24): 83MB FETCH / 66us = 1.5 TB/s of 128B-random HBM =
//      DRAM random-access ceiling (~20% of peak). Bytes/segments/dep-chain/
//      MLP-depth levers all individually nulled. aggmm+aggsum done.
// TAIL FLOOR (R20b/R25/R26): bucket-sort machinery resisted 3 attacks.
//      R25 (fineB rebalance + 2x buckets): null. R26 (per-node slot
//      scatter): -160us — sparse-region 4B scatter pays full 64B line RMW
//      (WRITE_SIZE 97MB vs 6.5 useful). Lesson: scattered writes are cheap
//      ONLY when line-dense (bucket windows); R20's "free" was conditional.
// ---------------------------------------------------------------------------

#define BSHIFT 8
#define BSZ    256          // nodes per bucket
#define MAXBKT 512          // LDS sizing bound (N <= 131072)
#define CPAD   32           // 1 counter / 128 B line for global cursors
#define CAPSH  13           // 8192 staged/col slots per bucket

typedef _Float16 half8 __attribute__((ext_vector_type(8)));
typedef float f32x4 __attribute__((ext_vector_type(4)));
typedef float f32x2 __attribute__((ext_vector_type(2)));

#define RFL __builtin_amdgcn_readfirstlane

// ---- prep: bin | layer1(4-dim h0) | cvtW | bounds | zero(sums) ----
__global__ __launch_bounds__(512) void k_prep(
        const float* __restrict__ x, const float* __restrict__ Wd1,
        const float* __restrict__ bd1, __half* __restrict__ h0,
        const float* __restrict__ W2, const float* __restrict__ W3,
        __half* __restrict__ WT2, __half* __restrict__ WT3,
        const int* __restrict__ batch, int* __restrict__ gs,
        const int* __restrict__ src, const int* __restrict__ dst,
        int* __restrict__ bktFill, int* __restrict__ staged,
        float* __restrict__ sums,
        int N, int NG, int E, int nbkt, int BINB, int L1B, int NB1) {
    __shared__ int hh[MAXBKT], base[MAXBKT], cur[MAXBKT];
    int bid = blockIdx.x;
    int t = threadIdx.x;
    if (bid < BINB) {
        // ---- bin: 4096 edges/block; LDS hist -> reservation -> scatter
        for (int i = t; i < nbkt; i += 512) { hh[i] = 0; cur[i] = 0; }
        __syncthreads();
        int e0 = bid * 4096 + t;
#pragma unroll
        for (int k = 0; k < 8; k++) {
            int e = e0 + k * 512;
            if (e < E) atomicAdd(&hh[dst[e] >> BSHIFT], 1);
        }
        __syncthreads();
        for (int i = t; i < nbkt; i += 512)
            base[i] = hh[i] ? atomicAdd(&bktFill[(size_t)i * CPAD], hh[i]) : 0;
        __syncthreads();
#pragma unroll
        for (int k = 0; k < 8; k++) {
            int e = e0 + k * 512;
            if (e < E) {
                int d = dst[e], s = src[e];
                int b = d >> BSHIFT;
                int off = atomicAdd(&cur[b], 1);
                staged[((size_t)b << CAPSH) + base[b] + off] =
                    ((d & (BSZ - 1)) << 17) | s;
            }
        }
    } else if (bid < BINB + L1B) {
        // ---- layer1 front: h0 = relu(x@Wd1+bd1), 4-dim fp16 (8 B/node)
        int node = (bid - BINB) * 512 + t;
        if (node < N) {
            float4 xv = ((const float4*)x)[node];
            float h[4];
#pragma unroll
            for (int k = 0; k < 4; k++) {
                float v = xv.x * Wd1[k] + xv.y * Wd1[4 + k]
                        + xv.z * Wd1[8 + k] + xv.w * Wd1[12 + k] + bd1[k];
                h[k] = fmaxf(v, 0.f);
            }
            __half2 o01 = __floats2half2_rn(h[0], h[1]);
            __half2 o23 = __floats2half2_rn(h[2], h[3]);
            uint2 pk;
            pk.x = *(unsigned*)&o01; pk.y = *(unsigned*)&o23;
            *(uint2*)(h0 + (size_t)node * 4) = pk;
        }
    } else if (bid < BINB + L1B + 32) {
        // ---- cvtW: W fp32 [k][n] -> WT fp16 [n][k], both layers
        int t2 = (bid - BINB - L1B) * 512 + t;      // 0..16383
        int k = t2 >> 7, nn = t2 & 127;
        WT2[nn * 128 + k] = __float2half_rn(W2[t2]);
        WT3[nn * 128 + k] = __float2half_rn(W3[t2]);
    } else if (bid < BINB + L1B + 32 + NB1) {
        // ---- bounds: batch sorted -> per-graph node ranges
        int i = (bid - BINB - L1B - 32) * 512 + t;
        if (i >= N) return;
        int b = batch[i];
        int prev = (i == 0) ? -1 : batch[i - 1];
        for (int g2 = prev + 1; g2 <= b; ++g2) gs[g2] = i;
        if (i == N - 1)
            for (int g2 = b + 1; g2 <= NG; ++g2) gs[g2] = N;
    } else {
        // ---- zero sums
        int idx = (bid - BINB - L1B - 32 - NB1) * 512 + t;
        if (idx < NG * 128) sums[idx] = 0.f;
    }
}

// ---- per-bucket: load+hist in LDS -> scan -> scatter; + dis & h0s=dis*h0 ----
__global__ __launch_bounds__(1024) void k_fineB(
        const int* __restrict__ staged, const int* __restrict__ bktFill,
        int2* __restrict__ rpe, float* __restrict__ dis,
        int* __restrict__ col, const __half* __restrict__ h0,
        __half* __restrict__ h0s, int N) {
    __shared__ int sEnt[1 << CAPSH];        // 32 KB bucket cache
    __shared__ int cnt[BSZ];
    __shared__ int incl[BSZ];
    int b = blockIdx.x;
    int lo = b << CAPSH;
    int cntE = bktFill[(size_t)b * CPAD];
    int n0 = b << BSHIFT;
    int tid = threadIdx.x;
    if (tid < BSZ) cnt[tid] = 0;
    __syncthreads();
    // fused: stage entries in LDS + histogram
    for (int e = tid; e < cntE; e += 1024) {
        int v = staged[lo + e];
        sEnt[e] = v;
        atomicAdd(&cnt[v >> 17], 1);
    }
    __syncthreads();
    int v = 0;
    if (tid < BSZ) { v = cnt[tid]; incl[tid] = v; }
    for (int off = 1; off < BSZ; off <<= 1) {
        __syncthreads();
        int t = (tid < BSZ && tid >= off) ? incl[tid - off] : 0;
        __syncthreads();
        if (tid < BSZ) incl[tid] += t;
    }
    __syncthreads();
    int myofs = 0;
    if (tid < BSZ) {
        myofs = incl[tid] - v;                 // exclusive
        int node = n0 + tid;
        if (node < N) {
            rpe[node] = make_int2(lo + myofs, lo + myofs + v);
            float dloc = rsqrtf((float)(v + 1));   // +1: self-loop
            dis[node] = dloc;
            uint2 hv = *(const uint2*)(h0 + (size_t)node * 4);
            float2 a01 = __half22float2(*(__half2*)&hv.x);
            float2 a23 = __half22float2(*(__half2*)&hv.y);
            __half2 o01 = __floats2half2_rn(a01.x * dloc, a01.y * dloc);
            __half2 o23 = __floats2half2_rn(a23.x * dloc, a23.y * dloc);
            uint2 pk;
            pk.x = *(unsigned*)&o01; pk.y = *(unsigned*)&o23;
            *(uint2*)(h0s + (size_t)node * 4) = pk;
        }
    }
    __syncthreads();
    // reuse incl[] as base table, cnt[] as cursors
    if (tid < BSZ) { incl[tid] = myofs; cnt[tid] = 0; }
    __syncthreads();
    for (int e = tid; e < cntE; e += 1024) {
        int ent = sEnt[e];
        int dl = ent >> 17;
        int pos = lo + incl[dl] + atomicAdd(&cnt[dl], 1);
        col[pos] = ent & 0x1FFFF;
    }
}

// ---- helpers ----
__device__ __forceinline__ void addv4(float a[4], uint2 v) {
    float2 x01 = __half22float2(*(__half2*)&v.x);
    float2 x23 = __half22float2(*(__half2*)&v.y);
    a[0] += x01.x; a[1] += x01.y; a[2] += x23.x; a[3] += x23.y;
}

// ---- fp8 helpers: pack 8 fp32 (one seg of a row) -> uint2 of e4m3 ----
__device__ __forceinline__ uint2 pack_fp8x8(const float v[8]) {
    int a = 0, b = 0;
    a = __builtin_amdgcn_cvt_pk_fp8_f32(v[0], v[1], a, false);
    a = __builtin_amdgcn_cvt_pk_fp8_f32(v[2], v[3], a, true);
    b = __builtin_amdgcn_cvt_pk_fp8_f32(v[4], v[5], b, false);
    b = __builtin_amdgcn_cvt_pk_fp8_f32(v[6], v[7], b, true);
    return make_uint2((unsigned)a, (unsigned)b);
}

__device__ __forceinline__ void accf8(float acc[4], unsigned u) {
    f32x2 lo = __builtin_amdgcn_cvt_pk_f32_fp8(u, false);
    f32x2 hi = __builtin_amdgcn_cvt_pk_f32_fp8(u, true);
    acc[0] += lo[0]; acc[1] += lo[1]; acc[2] += hi[0]; acc[3] += hi[1];
}

// ---- fused layer1: 4-dim agg (16 threads/node, 1 thread/edge at deg~16,
// h0s L2-resident) + 16-lane shfl reduce + MFMA back-end.
__global__ __launch_bounds__(256) void k_aggL1(
        const __half* __restrict__ h0s, const int2* __restrict__ rpe,
        const float* __restrict__ dis, const int* __restrict__ col,
        const float* __restrict__ Wg1, const float* __restrict__ b1,
        const __half* __restrict__ WT2, unsigned char* __restrict__ qout,
        int n) {
    __shared__ float sW[512];
    __shared__ float sB[128];
    __shared__ float sAgg[16][4];
    __shared__ float sDis[16];
    __shared__ _Float16 sH[16 * 136];
    __shared__ _Float16 sO[16 * 136];
    int t = threadIdx.x;
    sW[t] = Wg1[t];
    sW[t + 256] = Wg1[t + 256];
    if (t < 128) sB[t] = b1[t];
    int node0 = blockIdx.x * 16;
    if (t < 16) sDis[t] = (node0 + t < n) ? dis[node0 + t] : 0.f;
    int g = t >> 4, sub = t & 15;
    int ng = node0 + g;
    float a[4] = {0.f, 0.f, 0.f, 0.f};
    if (ng < n) {
        int2 re = rpe[ng];
        int r0 = re.x, r1 = re.y;
        for (int e = r0 + sub; e < r1; e += 16) {
            uint2 vv = *(const uint2*)(h0s + (size_t)col[e] * 4);
            addv4(a, vv);
        }
    }
    // reduce across the node's 16 lanes (same wave: groups are 16-aligned)
#pragma unroll
    for (int k = 0; k < 4; k++) {
        a[k] += __shfl_xor(a[k], 1);
        a[k] += __shfl_xor(a[k], 2);
        a[k] += __shfl_xor(a[k], 4);
        a[k] += __shfl_xor(a[k], 8);
    }
    if (ng < n) {
        // self-loop (h0s pre-scaled by dis): add once, post-reduce
        uint2 sv = *(const uint2*)(h0s + (size_t)ng * 4);
        float2 s01 = __half22float2(*(__half2*)&sv.x);
        float2 s23 = __half22float2(*(__half2*)&sv.y);
        a[0] += s01.x; a[1] += s01.y; a[2] += s23.x; a[3] += s23.y;
        float di = dis[ng];
        // static-index select (no runtime index into reg array)
        float av = (sub == 0) ? a[0] : (sub == 1) ? a[1]
                 : (sub == 2) ? a[2] : a[3];
        if (sub < 4) sAgg[g][sub] = av * di;    // same-wave write/read ok
    }
    __syncthreads();    // sW/sB/sDis/sAgg ready for all waves
    int row = t >> 4, seg = t & 15;
    int nodeR = node0 + row;
    float4 av4 = make_float4(sAgg[row][0], sAgg[row][1],
                             sAgg[row][2], sAgg[row][3]);
    half8 hv;
#pragma unroll
    for (int u = 0; u < 8; u++) {
        int j = seg * 8 + u;
        float vv = sB[j] + av4.x * sW[j] + av4.y * sW[128 + j]
                 + av4.z * sW[256 + j] + av4.w * sW[384 + j];
        hv[u] = (_Float16)fmaxf(vv, 0.f);
    }
    *(half8*)&sH[row * 136 + seg * 8] = hv;
    __syncthreads();
    // mm: wave covers cols [wave*32, wave*32+32) for all 16 rows
    int wave = t >> 6, lane = t & 63;
    int q = lane >> 4, c = lane & 15;
    int n0c = wave * 32;
    f32x4 acc0 = {0.f, 0.f, 0.f, 0.f}, acc1 = {0.f, 0.f, 0.f, 0.f};
#pragma unroll
    for (int ks = 0; ks < 4; ks++) {
        int k0 = ks * 32;
        half8 av  = *(half8*)&sH[c * 136 + k0 + q * 8];
        half8 b0 = *(const half8*)(WT2 + (size_t)(n0c + c) * 128 + k0 + q * 8);
        half8 b1v = *(const half8*)(WT2 + (size_t)(n0c + 16 + c) * 128 + k0 + q * 8);
        acc0 = __builtin_amdgcn_mfma_f32_16x16x32_f16(av, b0, acc0, 0, 0, 0);
        acc1 = __builtin_amdgcn_mfma_f32_16x16x32_f16(av, b1v, acc1, 0, 0, 0);
    }
#pragma unroll
    for (int r = 0; r < 4; r++) {
        int rr = q * 4 + r;
        sO[rr * 136 + n0c + c]      = (_Float16)(acc0[r] * sDis[rr]);
        sO[rr * 136 + n0c + 16 + c] = (_Float16)(acc1[r] * sDis[rr]);
    }
    __syncthreads();
    // fp8 pack epilogue
    half8 ov = *(half8*)&sO[row * 136 + seg * 8];
    float vv[8];
#pragma unroll
    for (int u = 0; u < 8; u++) vv[u] = (float)ov[u];
    if (nodeR < n)
        *(uint2*)(qout + (size_t)nodeR * 128 + seg * 8) = pack_fp8x8(vv);
}

// ---- fp8 gather core (R23 prefetch, R24 8-deep): half-wave hf covers
// edge 2p+hf's FULL row (4 B/lane = 4 e4m3, lanes sl=0..31 -> feats
// 4sl..4sl+3 = 128 B row, 2 segments/edge).
__device__ __forceinline__ void agg_chunk_f8(
        const unsigned char* __restrict__ g, int colv, int nloc,
        int hf, int sl, float acc[4]) {
    int npair = nloc >> 1;
    int p = 0;
    for (; p + 7 < npair; p += 8) {
        int i2 = p * 2 + hf;
        int s0 = __shfl(colv, i2);
        int s1 = __shfl(colv, i2 + 2);
        int s2 = __shfl(colv, i2 + 4);
        int s3 = __shfl(colv, i2 + 6);
        int s4 = __shfl(colv, i2 + 8);
        int s5 = __shfl(colv, i2 + 10);
        int s6 = __shfl(colv, i2 + 12);
        int s7 = __shfl(colv, i2 + 14);
        unsigned u0 = *(const unsigned*)(g + (size_t)s0 * 128 + sl * 4);
        unsigned u1 = *(const unsigned*)(g + (size_t)s1 * 128 + sl * 4);
        unsigned u2 = *(const unsigned*)(g + (size_t)s2 * 128 + sl * 4);
        unsigned u3 = *(const unsigned*)(g + (size_t)s3 * 128 + sl * 4);
        unsigned u4 = *(const unsigned*)(g + (size_t)s4 * 128 + sl * 4);
        unsigned u5 = *(const unsigned*)(g + (size_t)s5 * 128 + sl * 4);
        unsigned u6 = *(const unsigned*)(g + (size_t)s6 * 128 + sl * 4);
        unsigned u7 = *(const unsigned*)(g + (size_t)s7 * 128 + sl * 4);
        accf8(acc, u0); accf8(acc, u1); accf8(acc, u2); accf8(acc, u3);
        accf8(acc, u4); accf8(acc, u5); accf8(acc, u6); accf8(acc, u7);
    }
    for (; p + 3 < npair; p += 4) {
        int i2 = p * 2 + hf;
        int s0 = __shfl(colv, i2);
        int s1 = __shfl(colv, i2 + 2);
        int s2 = __shfl(colv, i2 + 4);
        int s3 = __shfl(colv, i2 + 6);
        unsigned u0 = *(const unsigned*)(g + (size_t)s0 * 128 + sl * 4);
        unsigned u1 = *(const unsigned*)(g + (size_t)s1 * 128 + sl * 4);
        unsigned u2 = *(const unsigned*)(g + (size_t)s2 * 128 + sl * 4);
        unsigned u3 = *(const unsigned*)(g + (size_t)s3 * 128 + sl * 4);
        accf8(acc, u0); accf8(acc, u1); accf8(acc, u2); accf8(acc, u3);
    }
    for (; p < npair; ++p) {
        int s0 = __shfl(colv, p * 2 + hf);
        unsigned u0 = *(const unsigned*)(g + (size_t)s0 * 128 + sl * 4);
        accf8(acc, u0);
    }
    if (nloc & 1) {                         // odd tail: half 1 contributes 0
        int s0 = __shfl(colv, nloc - 1);
        unsigned u0 = *(const unsigned*)(g + (size_t)s0 * 128 + sl * 4);
        if (!hf) accf8(acc, u0);
    }
}

// per-node agg using a PREFETCHED colv (caller loads col[r0+lane] before
// any gathers). deg>64: rare chunk loop reloads col inside.
__device__ __forceinline__ void agg_node_f8v(
        const unsigned char* __restrict__ g, const int* __restrict__ col,
        int r0, int r1, int node, int colv, int hf, int sl, int lane,
        float acc[4]) {
    acc[0] = acc[1] = acc[2] = acc[3] = 0.f;
    if (!hf) {   // self-loop on half 0 only (rows pre-scaled by dis)
        unsigned su = *(const unsigned*)(g + (size_t)node * 128 + sl * 4);
        accf8(acc, su);
    }
    int deg = r1 - r0;
    int nloc = deg < 64 ? deg : 64;
    agg_chunk_f8(g, colv, nloc, hf, sl, acc);
    for (int base = r0 + 64; base < r1; base += 64) {   // rare: deg > 64
        int cv = col[base + lane];
        int nl = r1 - base; if (nl > 64) nl = 64;
        agg_chunk_f8(g, cv, nl, hf, sl, acc);
    }
#pragma unroll
    for (int k = 0; k < 4; k++) acc[k] += __shfl_xor(acc[k], 32);
}

// fused GCN layer (fp8 in / fp8 out): block = 16 nodes (4 waves x 4
// serial). Prefetch-then-burst agg -> LDS rows -> mfma -> fp8 rows.
__global__ __launch_bounds__(256) void k_aggmm(
        const unsigned char* __restrict__ qin, const int2* __restrict__ rpe,
        const int* __restrict__ col, const float* __restrict__ dis,
        const float* __restrict__ bias, const __half* __restrict__ WT,
        unsigned char* __restrict__ qout, int n) {
    __shared__ _Float16 sH[16 * 136];
    __shared__ _Float16 sO[16 * 136];
    __shared__ float sDis[16];
    int t = threadIdx.x;
    int wave = t >> 6, lane = t & 63;
    int hf = lane >> 5, sl = lane & 31;
    int node0 = blockIdx.x * 16;
    if (t < 16) sDis[t] = (node0 + t < n) ? dis[node0 + t] : 0.f;
    float4 bb = ((const float4*)bias)[sl];
    int nodeA = node0 + wave * 4;
    // --- prefetch: 4x rpe then 4x col vectors, BEFORE any gather ---
    int nd0 = RFL(nodeA), nd1 = RFL(nodeA + 1);
    int nd2 = RFL(nodeA + 2), nd3 = RFL(nodeA + 3);
    int r00 = 0, r10 = 0, r01 = 0, r11 = 0;
    int r02 = 0, r12 = 0, r03 = 0, r13 = 0;
    if (nd0 < n) { int2 re = rpe[nd0]; r00 = RFL(re.x); r10 = RFL(re.y); }
    if (nd1 < n) { int2 re = rpe[nd1]; r01 = RFL(re.x); r11 = RFL(re.y); }
    if (nd2 < n) { int2 re = rpe[nd2]; r02 = RFL(re.x); r12 = RFL(re.y); }
    if (nd3 < n) { int2 re = rpe[nd3]; r03 = RFL(re.x); r13 = RFL(re.y); }
    int cv0 = col[r00 + lane];
    int cv1 = col[r01 + lane];
    int cv2 = col[r02 + lane];
    int cv3 = col[r03 + lane];
    float acc[4];
#define AGGMM_NODE(I, ND, R0, R1, CV)                                        \
    if (ND < n) {                                                            \
        agg_node_f8v(qin, col, R0, R1, ND, CV, hf, sl, lane, acc);           \
        if (hf == 0) {                                                       \
            float di = sDis[wave * 4 + I];                                   \
            __half2 o01 = __floats2half2_rn(                                 \
                fmaxf(fmaf(di, acc[0], bb.x), 0.f),                          \
                fmaxf(fmaf(di, acc[1], bb.y), 0.f));                         \
            __half2 o23 = __floats2half2_rn(                                 \
                fmaxf(fmaf(di, acc[2], bb.z), 0.f),                          \
                fmaxf(fmaf(di, acc[3], bb.w), 0.f));                         \
            uint2 pk;                                                        \
            pk.x = *(unsigned*)&o01; pk.y = *(unsigned*)&o23;                \
            *(uint2*)&sH[(wave * 4 + I) * 136 + sl * 4] = pk;                \
        }                                                                    \
    }
    __syncthreads();   // sDis ready (also orders sH writes vs later reads)
    AGGMM_NODE(0, nd0, r00, r10, cv0)
    AGGMM_NODE(1, nd1, r01, r11, cv1)
    AGGMM_NODE(2, nd2, r02, r12, cv2)
    AGGMM_NODE(3, nd3, r03, r13, cv3)
#undef AGGMM_NODE
    __syncthreads();
    // mm: wave covers cols [wave*32, wave*32+32) for all 16 rows
    int q = lane >> 4, c = lane & 15;
    int n0 = wave * 32;
    f32x4 acc0 = {0.f, 0.f, 0.f, 0.f}, acc1 = {0.f, 0.f, 0.f, 0.f};
#pragma unroll
    for (int ks = 0; ks < 4; ks++) {
        int k0 = ks * 32;
        half8 a  = *(half8*)&sH[c * 136 + k0 + q * 8];
        half8 b0 = *(const half8*)(WT + (size_t)(n0 + c) * 128 + k0 + q * 8);
        half8 b1 = *(const half8*)(WT + (size_t)(n0 + 16 + c) * 128 + k0 + q * 8);
        acc0 = __builtin_amdgcn_mfma_f32_16x16x32_f16(a, b0, acc0, 0, 0, 0);
        acc1 = __builtin_amdgcn_mfma_f32_16x16x32_f16(a, b1, acc1, 0, 0, 0);
    }
#pragma unroll
    for (int r = 0; r < 4; r++) {
        int rr = q * 4 + r;
        sO[rr * 136 + n0 + c]      = (_Float16)(acc0[r] * sDis[rr]);
        sO[rr * 136 + n0 + 16 + c] = (_Float16)(acc1[r] * sDis[rr]);
    }
    __syncthreads();
    // fp8 pack epilogue
    int lr2 = t >> 4, seg = t & 15;
    int rowN = node0 + lr2;
    half8 ov = *(half8*)&sO[lr2 * 136 + seg * 8];
    float vv[8];
#pragma unroll
    for (int u = 0; u < 8; u++) vv[u] = (float)ov[u];
    if (rowN < n)
        *(uint2*)(qout + (size_t)rowN * 128 + seg * 8) = pack_fp8x8(vv);
}

// fused layer-3 agg + mean-pool (fp8 input). Single-graph blocks (~92%):
// per-wave register partials -> private LDS slots -> one barrier ->
// 128 global atomics. Boundary: per-wave flush.
__global__ __launch_bounds__(256) void k_aggsum(
        const unsigned char* __restrict__ qin, const int2* __restrict__ rpe,
        const int* __restrict__ col, const float* __restrict__ dis,
        const float* __restrict__ bias, const int* __restrict__ batch,
        float* __restrict__ sums, int n) {
    __shared__ float ls[4][128];
    int t = threadIdx.x;
    int wave = t >> 6, lane = t & 63;
    int hf = lane >> 5, sl = lane & 31;
    int nodeBase = blockIdx.x * 16;
    if (nodeBase >= n) return;
    int lastNode = min(nodeBase + 15, n - 1);
    int b0 = RFL(batch[nodeBase]);
    bool uni = (RFL(batch[lastNode]) == b0);
    float4 bb = ((const float4*)bias)[sl];
    float sx[4] = {0.f, 0.f, 0.f, 0.f};
    int curb = b0;
    int nodeA = nodeBase + wave * 4;
    // --- prefetch: 4x rpe then 4x col vectors ---
    int nd0 = RFL(nodeA), nd1 = RFL(nodeA + 1);
    int nd2 = RFL(nodeA + 2), nd3 = RFL(nodeA + 3);
    int r00 = 0, r10 = 0, r01 = 0, r11 = 0;
    int r02 = 0, r12 = 0, r03 = 0, r13 = 0;
    if (nd0 < n) { int2 re = rpe[nd0]; r00 = RFL(re.x); r10 = RFL(re.y); }
    if (nd1 < n) { int2 re = rpe[nd1]; r01 = RFL(re.x); r11 = RFL(re.y); }
    if (nd2 < n) { int2 re = rpe[nd2]; r02 = RFL(re.x); r12 = RFL(re.y); }
    if (nd3 < n) { int2 re = rpe[nd3]; r03 = RFL(re.x); r13 = RFL(re.y); }
    int cv0 = col[r00 + lane];
    int cv1 = col[r01 + lane];
    int cv2 = col[r02 + lane];
    int cv3 = col[r03 + lane];
    float acc[4];
#define AGGSUM_NODE(ND, R0, R1, CV)                                          \
    if (ND < n) {                                                            \
        agg_node_f8v(qin, col, R0, R1, ND, CV, hf, sl, lane, acc);           \
        float di = dis[ND];                                                  \
        float o0 = fmaxf(fmaf(di, acc[0], bb.x), 0.f);                       \
        float o1 = fmaxf(fmaf(di, acc[1], bb.y), 0.f);                       \
        float o2 = fmaxf(fmaf(di, acc[2], bb.z), 0.f);                       \
        float o3 = fmaxf(fmaf(di, acc[3], bb.w), 0.f);                       \
        if (!uni) {                                                          \
            int b = RFL(batch[ND]);                                          \
            if (b != curb) {                                                 \
                if (hf == 0) {                                               \
                    atomicAdd(&sums[(size_t)curb * 128 + sl * 4 + 0], sx[0]);\
                    atomicAdd(&sums[(size_t)curb * 128 + sl * 4 + 1], sx[1]);\
                    atomicAdd(&sums[(size_t)curb * 128 + sl * 4 + 2], sx[2]);\
                    atomicAdd(&sums[(size_t)curb * 128 + sl * 4 + 3], sx[3]);\
                }                                                            \
                sx[0] = sx[1] = sx[2] = sx[3] = 0.f;                         \
                curb = b;                                                    \
            }                                                                \
        }                                                                    \
        sx[0] += o0; sx[1] += o1; sx[2] += o2; sx[3] += o3;                  \
    }
    AGGSUM_NODE(nd0, r00, r10, cv0)
    AGGSUM_NODE(nd1, r01, r11, cv1)
    AGGSUM_NODE(nd2, r02, r12, cv2)
    AGGSUM_NODE(nd3, r03, r13, cv3)
#undef AGGSUM_NODE
    if (uni) {
        // slot-exclusive LDS write (hf==0 lanes cover all 128 feats)
        if (hf == 0) {
            ls[wave][sl * 4 + 0] = sx[0];
            ls[wave][sl * 4 + 1] = sx[1];
            ls[wave][sl * 4 + 2] = sx[2];
            ls[wave][sl * 4 + 3] = sx[3];
        }
        __syncthreads();
        if (t < 128) {
            float v = ls[0][t] + ls[1][t] + ls[2][t] + ls[3][t];
            atomicAdd(&sums[(size_t)b0 * 128 + t], v);
        }
    } else {
        if (hf == 0) {
            atomicAdd(&sums[(size_t)curb * 128 + sl * 4 + 0], sx[0]);
            atomicAdd(&sums[(size_t)curb * 128 + sl * 4 + 1], sx[1]);
            atomicAdd(&sums[(size_t)curb * 128 + sl * 4 + 2], sx[2]);
            atomicAdd(&sums[(size_t)curb * 128 + sl * 4 + 3], sx[3]);
        }
    }
}

// head: pooled = sums/cnt; out = pooled @ Wd2 + bd2. One block per graph.
__global__ __launch_bounds__(128) void k_head(
        const float* __restrict__ sums, const int* __restrict__ gs,
        const float* __restrict__ Wd2, const float* __restrict__ bd2,
        float* __restrict__ out) {
    int gidx = blockIdx.x;
    int j = threadIdx.x;
    int c = gs[gidx + 1] - gs[gidx];
    float inv = 1.0f / (float)(c > 1 ? c : 1);
    __shared__ float sp[128];
    sp[j] = sums[(size_t)gidx * 128 + j] * inv;
    __syncthreads();
    float o = bd2[j];
#pragma unroll 8
    for (int k = 0; k < 128; k++) o = fmaf(sp[k], Wd2[k * 128 + j], o);
    out[gidx * 128 + j] = o;
}

extern "C" void kernel_launch(void* const* d_in, const int* in_sizes, int n_in,
                              void* d_out, int out_size, void* d_ws, size_t ws_size,
                              hipStream_t stream) {
    const float* x   = (const float*)d_in[0];
    const int*  ei   = (const int*)d_in[1];
    const int* batch = (const int*)d_in[2];
    const float* Wd1 = (const float*)d_in[3];
    const float* bd1 = (const float*)d_in[4];
    const float* Wg1 = (const float*)d_in[5];
    const float* bg1 = (const float*)d_in[6];
    const float* Wg2 = (const float*)d_in[7];
    const float* bg2 = (const float*)d_in[8];
    const float* Wg3 = (const float*)d_in[9];
    const float* bg3 = (const float*)d_in[10];
    const float* Wd2 = (const float*)d_in[11];
    const float* bd2 = (const float*)d_in[12];
    float* out = (float*)d_out;

    int N  = in_sizes[0] / 4;       // N_FEAT = 4
    int E  = in_sizes[1] / 2;       // edge_index is [2, E]
    int NG = out_size / 128;        // 512 graphs
    const int* srcIdx = ei;
    const int* dstIdx = ei + E;
    int nbkt = (N + BSZ - 1) >> BSHIFT;     // 391 for N=100000

    char* p = (char*)d_ws;
    auto alloc = [&](size_t bytes) -> char* {
        char* r = p;
        p += (bytes + 255) & ~(size_t)255;
        return r;
    };
    int*    bktFill = (int*)alloc((size_t)nbkt * CPAD * 4);
    int*    staged  = (int*)alloc(((size_t)nbkt << CAPSH) * 4);   // 12.8 MB
    int*    col     = (int*)alloc(((size_t)nbkt << CAPSH) * 4 + 256); // +slack
    int2*   rpe     = (int2*)alloc((size_t)N * 8);
    float*  dis     = (float*)alloc((size_t)N * 4);
    int*    gs      = (int*)alloc(((size_t)NG + 1) * 4);
    float*  sums    = (float*)alloc((size_t)NG * 128 * 4);
    __half* WT2     = (__half*)alloc(16384 * 2);
    __half* WT3     = (__half*)alloc(16384 * 2);
    unsigned char* qB = (unsigned char*)alloc((size_t)N * 128);   // 12.8 MB
    unsigned char* qA = (unsigned char*)alloc((size_t)N * 128);   // 12.8 MB
    __half* h0      = (__half*)alloc((size_t)N * 4 * 2);          // 0.8 MB
    __half* h0s     = (__half*)alloc((size_t)N * 4 * 2);          // 0.8 MB
    (void)ws_size; (void)n_in;

    int BINB = (E + 4095) / 4096;               // 391
    int L1B  = (N + 511) / 512;                 // 196
    int NB1  = (N + 511) / 512;                 // 196
    int ZB   = (NG * 128 + 511) / 512;          // 128
    int prepB = BINB + L1B + 32 + NB1 + ZB;
    int nb16  = (N + 15) / 16;                  // 6250

    hipMemsetAsync(bktFill, 0, (size_t)nbkt * CPAD * 4, stream);  // 50 KB

    k_prep<<<prepB, 512, 0, stream>>>(x, Wd1, bd1, h0, Wg2, Wg3, WT2, WT3,
                                      batch, gs, srcIdx, dstIdx, bktFill,
                                      staged, sums, N, NG, E, nbkt,
                                      BINB, L1B, NB1);
    k_fineB<<<nbkt, 1024, 0, stream>>>(staged, bktFill, rpe, dis, col,
                                       h0, h0s, N);

    // layer1: fused 4-dim agg (16 thr/node, L2-resident) + MFMA back-end:
    // qB = fp8(dis * (relu(agg@Wg1+b1) @ W2))
    k_aggL1<<<nb16, 256, 0, stream>>>(h0s, rpe, dis, col, Wg1, bg1, WT2,
                                      qB, N);
    // layer2: fp8-row fused agg+mm -> qA
    k_aggmm<<<nb16, 256, 0, stream>>>(qB, rpe, col, dis, bg2, WT3, qA, N);
    // layer3 + pool (fp8 input)
    k_aggsum<<<nb16, 256, 0, stream>>>(qA, rpe, col, dis, bg3, batch,
                                       sums, N);

    k_head<<<NG, 128, 0, stream>>>(sums, gs, Wd2, bd2, out);
}